// Round 8
// baseline (232.213 us; speedup 1.0000x reference)
//
#include <hip/hip_runtime.h>

#define NEG_SLOPE 0.2f
static constexpr int IN_F = 128;   // input feature dim
static constexpr int NHEAD = 4;
static constexpr int CH = 64;      // channels per head
static constexpr int HC = 256;     // NHEAD*CH
static constexpr int SC_EPB = 2000;  // edges per scatter block
static constexpr int CB_CAP = 6144;  // csr_build LDS sort capacity

static __host__ size_t align256(size_t v) { return (v + 255) & ~((size_t)255); }

__device__ inline ushort f2bf(float f) {          // round-to-nearest-even fp32->bf16
    unsigned u = __float_as_uint(f);
    unsigned r = u + 0x7FFFu + ((u >> 16) & 1u);
    return (ushort)(r >> 16);
}
__device__ inline float bf2f(ushort s) { return __uint_as_float(((unsigned)s) << 16); }
__device__ inline ushort f2h(float f) {
    _Float16 h = (_Float16)f;
    return *(ushort*)&h;
}
__device__ inline float h2f(ushort u) {
    _Float16 h = *(_Float16*)&u;
    return (float)h;
}

typedef short s16x8 __attribute__((ext_vector_type(8)));    // 8 bf16 = 4 VGPR
typedef float f32x16 __attribute__((ext_vector_type(16)));  // 32x32 accumulator

// ---- prep: Wt[n][k] = bf16(W[k][n]) + zero counters + rowptr[N] ------------
__global__ __launch_bounds__(256) void prep_kernel(
    const float* __restrict__ W, ushort* __restrict__ Wt,
    int* __restrict__ ccnt, int* __restrict__ cur0,
    int* __restrict__ rowptr, int N, int Etot)
{
    int f = blockIdx.x * 256 + threadIdx.x;     // 32768 elements
    int k = f >> 8;                             // 0..127
    int n = f & 255;                            // 0..255
    Wt[n * IN_F + k] = f2bf(W[(size_t)k * HC + n]);
    if (blockIdx.x == 0) {
        ccnt[threadIdx.x] = 0;
        cur0[threadIdx.x] = 0;
        if (threadIdx.x == 0) rowptr[N] = Etot;
    }
}

// ---- MFMA GEMM (2 heads/block) + fused edge bucket-count -------------------
__global__ __launch_bounds__(256) void gemm_mfma_kernel(
    const float* __restrict__ x, const ushort* __restrict__ Wt,
    const float* __restrict__ att_src, const float* __restrict__ att_dst,
    ushort* __restrict__ hb, float* __restrict__ a_src, float* __restrict__ a_dst,
    const int* __restrict__ dst, int* __restrict__ coarse_cnt,
    int E, int epb, int NTB, int NB, int N)
{
    constexpr int LDK = 136;            // padded K stride (ushort elems)
    __shared__ ushort As[64 * LDK];     // x tile [m][k] bf16
    __shared__ ushort Bs[128 * LDK];    // Wt tile [n][k] bf16
    ushort* Hs = As;                    // h-tile aliases As after MFMA

    const int t = threadIdx.x;

    if (blockIdx.x >= NTB) {            // ---- bucket-count role ----
        int* hist = (int*)As;
        hist[t] = 0;
        __syncthreads();
        int slice = (blockIdx.x - NTB) * 2 + blockIdx.y;
        int lo = slice * epb;
        int hi = min(E, lo + epb);
        for (int i = lo + t; i < hi; i += 256)
            atomicAdd(&hist[((unsigned)dst[i]) >> 8], 1);
        __syncthreads();
        if (t < NB && hist[t]) atomicAdd(&coarse_cnt[t], hist[t]);
        return;
    }

    const int m0 = blockIdx.x * 64;
    const int n0 = blockIdx.y * 128;    // col offset in h (2 heads)

    #pragma unroll
    for (int u = 0; u < 8; ++u) {
        int f = t + 256 * u;
        int r = f >> 5;
        int k4 = (f & 31) * 4;
        int row = m0 + r;
        float4 v = make_float4(0.f, 0.f, 0.f, 0.f);
        if (row < N) v = *(const float4*)(x + (size_t)row * IN_F + k4);
        ushort4 o;
        o.x = f2bf(v.x); o.y = f2bf(v.y); o.z = f2bf(v.z); o.w = f2bf(v.w);
        *(ushort4*)&As[r * LDK + k4] = o;
    }
    #pragma unroll
    for (int u = 0; u < 8; ++u) {
        int f = t + 256 * u;
        int n = f >> 4;
        int k8 = (f & 15) * 8;
        uint4 v = *(const uint4*)(Wt + (size_t)(n0 + n) * IN_F + k8);
        *(uint4*)&Bs[n * LDK + k8] = v;
    }
    __syncthreads();

    const int w = t >> 6;
    const int lane = t & 63;
    const int mrow = 32 * (w >> 1) + (lane & 31);
    const int nbase = 64 * (w & 1) + (lane & 31);
    const int kq = (lane >> 5) * 8;

    f32x16 acc0 = {}, acc1 = {};
    #pragma unroll
    for (int s = 0; s < 8; ++s) {
        s16x8 af = *(const s16x8*)&As[mrow * LDK + 16 * s + kq];
        s16x8 b0 = *(const s16x8*)&Bs[nbase * LDK + 16 * s + kq];
        s16x8 b1 = *(const s16x8*)&Bs[(nbase + 32) * LDK + 16 * s + kq];
        acc0 = __builtin_amdgcn_mfma_f32_32x32x16_bf16(af, b0, acc0, 0, 0, 0);
        acc1 = __builtin_amdgcn_mfma_f32_32x32x16_bf16(af, b1, acc1, 0, 0, 0);
    }
    __syncthreads();

    {
        int rbase = 4 * (lane >> 5) + 32 * (w >> 1);
        int c0 = 64 * (w & 1) + (lane & 31);
        #pragma unroll
        for (int r = 0; r < 16; ++r) {
            int rowL = rbase + (r & 3) + 8 * (r >> 2);
            Hs[rowL * LDK + c0]      = f2bf(acc0[r]);
            Hs[rowL * LDK + c0 + 32] = f2bf(acc1[r]);
        }
    }
    __syncthreads();

    {
        int r2 = t >> 2;
        int q = t & 3;
        int row = m0 + r2;
        uint4 p0 = *(const uint4*)&Hs[r2 * LDK + 32 * q];
        uint4 p1 = *(const uint4*)&Hs[r2 * LDK + 32 * q + 8];
        uint4 p2 = *(const uint4*)&Hs[r2 * LDK + 32 * q + 16];
        uint4 p3 = *(const uint4*)&Hs[r2 * LDK + 32 * q + 24];
        if (row < N) {
            ushort* dsth = hb + (size_t)row * HC + n0 + 32 * q;
            *(uint4*)(dsth)      = p0;
            *(uint4*)(dsth + 8)  = p1;
            *(uint4*)(dsth + 16) = p2;
            *(uint4*)(dsth + 24) = p3;
        }
        int hq = 2 * blockIdx.y + (q >> 1);
        int cb = (q & 1) * 32;
        const float* asp = att_src + hq * CH + cb;
        const float* adp = att_dst + hq * CH + cb;
        unsigned uu[16] = { p0.x, p0.y, p0.z, p0.w, p1.x, p1.y, p1.z, p1.w,
                            p2.x, p2.y, p2.z, p2.w, p3.x, p3.y, p3.z, p3.w };
        float ps = 0.f, pd = 0.f;
        #pragma unroll
        for (int i = 0; i < 16; ++i) {
            float lo = bf2f((ushort)(uu[i] & 0xFFFFu));
            float hi = bf2f((ushort)(uu[i] >> 16));
            ps += lo * asp[2 * i] + hi * asp[2 * i + 1];
            pd += lo * adp[2 * i] + hi * adp[2 * i + 1];
        }
        ps += __shfl_xor(ps, 1, 64);
        pd += __shfl_xor(pd, 1, 64);
        if ((q & 1) == 0 && row < N) {
            a_src[(size_t)row * NHEAD + hq] = ps;
            a_dst[(size_t)row * NHEAD + hq] = pd;
        }
    }
}

// pass 3: scatter edges into bucket regions via block-local LDS counting sort.
// Each block re-derives ebase by scanning ccnt (scan_coarse dispatch removed).
// Packed value: (src << 8) | (dst & 255)
__global__ __launch_bounds__(256) void bucket_scatter(
    const int* __restrict__ src, const int* __restrict__ dst,
    const int* __restrict__ ccnt, int* __restrict__ cur0,
    unsigned* __restrict__ ebuf, int E)
{
    __shared__ int eb[256];             // exclusive base per bucket
    __shared__ int hist[256];
    __shared__ int lbase[256];
    __shared__ int gbase[256];
    __shared__ int cur[256];
    __shared__ unsigned sbuf[SC_EPB + 48];
    __shared__ unsigned char tb[SC_EPB + 48];
    int t = threadIdx.x;
    // scan ccnt -> exclusive ebase
    int cv = ccnt[t];
    eb[t] = cv;
    __syncthreads();
    #pragma unroll
    for (int off = 1; off < 256; off <<= 1) {
        int a = eb[t];
        int b = (t >= off) ? eb[t - off] : 0;
        __syncthreads();
        eb[t] = a + b;
        __syncthreads();
    }
    int myebase = eb[t] - cv;
    __syncthreads();
    eb[t] = myebase;

    int lo = blockIdx.x * SC_EPB;
    int hi = min(E, lo + SC_EPB);
    int cnt = hi - lo;
    hist[t] = 0;
    __syncthreads();
    unsigned pk[8]; int bk[8];
    #pragma unroll
    for (int u = 0; u < 8; ++u) {
        int i = lo + t + 256 * u;
        bk[u] = -1;
        if (i < hi) {
            unsigned d = (unsigned)dst[i];
            bk[u] = (int)(d >> 8);
            pk[u] = (((unsigned)src[i]) << 8) | (d & 255u);
            atomicAdd(&hist[bk[u]], 1);
        }
    }
    __syncthreads();
    int v = hist[t];
    lbase[t] = v;
    __syncthreads();
    #pragma unroll
    for (int off = 1; off < 256; off <<= 1) {
        int a = lbase[t];
        int b = (t >= off) ? lbase[t - off] : 0;
        __syncthreads();
        lbase[t] = a + b;
        __syncthreads();
    }
    int excl = lbase[t] - v;
    if (v) gbase[t] = eb[t] + atomicAdd(&cur0[t], v);   // reserve global run
    __syncthreads();
    lbase[t] = excl;
    cur[t] = excl;
    __syncthreads();
    #pragma unroll
    for (int u = 0; u < 8; ++u) {
        if (bk[u] >= 0) {
            int p = atomicAdd(&cur[bk[u]], 1);
            sbuf[p] = pk[u];
            tb[p] = (unsigned char)bk[u];
        }
    }
    __syncthreads();
    for (int j = t; j < cnt; j += 256) {
        int b = tb[j];
        ebuf[gbase[b] + j - lbase[b]] = sbuf[j];
    }
}

// pass 4: per-bucket CSR finalize + per-edge fp16 attention weights +
// per-node softmax denominators. LDS sort -> coalesced final writes.
__global__ __launch_bounds__(256) void csr_build(
    const unsigned* __restrict__ ebuf, const int* __restrict__ ccnt,
    const float* __restrict__ a_src, const float* __restrict__ a_dst,
    int* __restrict__ rowptr, int* __restrict__ csr_src,
    ushort* __restrict__ csr_w, float* __restrict__ dinv, int N, int NB)
{
    __shared__ int scn[256];
    __shared__ int hist[256];
    __shared__ int cur[256];
    __shared__ unsigned srt[CB_CAP];
    __shared__ float4 adl[256];
    __shared__ float denom[256][4];
    int b = blockIdx.x;
    int t = threadIdx.x;
    // derive ebase[b], ebase[b+1] from ccnt scan
    int cv = ccnt[t];
    scn[t] = cv;
    __syncthreads();
    #pragma unroll
    for (int off = 1; off < 256; off <<= 1) {
        int a = scn[t];
        int bb = (t >= off) ? scn[t - off] : 0;
        __syncthreads();
        scn[t] = a + bb;
        __syncthreads();
    }
    int lo = (b == 0) ? 0 : scn[b - 1];
    int hi = scn[b];
    __syncthreads();

    int n0 = b << 8;
    int ncnt = min(256, N - n0);
    int cnt = hi - lo;
    int cb = lo + n0;                   // global csr base (n0 = self loops before)

    if (t < ncnt) adl[t] = *(const float4*)(a_dst + (size_t)(n0 + t) * NHEAD);
    denom[t][0] = 0.f; denom[t][1] = 0.f; denom[t][2] = 0.f; denom[t][3] = 0.f;
    hist[t] = 0;
    __syncthreads();
    for (int i = lo + t; i < hi; i += 256)
        atomicAdd(&hist[ebuf[i] & 255u], 1);
    __syncthreads();
    int v = hist[t];
    scn[t] = v;
    __syncthreads();
    #pragma unroll
    for (int off = 1; off < 256; off <<= 1) {
        int a = scn[t];
        int bb = (t >= off) ? scn[t - off] : 0;
        __syncthreads();
        scn[t] = a + bb;
        __syncthreads();
    }
    int excl = scn[t] - v;
    if (t < ncnt) {                     // self loop first in each node segment
        int seg = cb + excl + t;
        rowptr[n0 + t] = seg;
        csr_src[seg] = n0 + t;
        float4 as4 = *(const float4*)(a_src + (size_t)(n0 + t) * NHEAD);
        float4 ad4 = adl[t];
        float e0 = as4.x + ad4.x; e0 = fmaxf(e0, NEG_SLOPE * e0);
        float e1 = as4.y + ad4.y; e1 = fmaxf(e1, NEG_SLOPE * e1);
        float e2 = as4.z + ad4.z; e2 = fmaxf(e2, NEG_SLOPE * e2);
        float e3 = as4.w + ad4.w; e3 = fmaxf(e3, NEG_SLOPE * e3);
        ushort4 pw;
        pw.x = f2h(__expf(e0)); pw.y = f2h(__expf(e1));
        pw.z = f2h(__expf(e2)); pw.w = f2h(__expf(e3));
        *(ushort4*)(csr_w + (size_t)seg * 4) = pw;
        denom[t][0] += h2f(pw.x); denom[t][1] += h2f(pw.y);
        denom[t][2] += h2f(pw.z); denom[t][3] += h2f(pw.w);
    }
    cur[t] = excl;
    __syncthreads();
    if (cnt <= CB_CAP) {
        for (int i = lo + t; i < hi; i += 256) {
            unsigned e = ebuf[i];
            int p = atomicAdd(&cur[e & 255u], 1);
            srt[p] = e;
        }
        __syncthreads();
        for (int j = t; j < cnt; j += 256) {
            unsigned e = srt[j];
            int ln = (int)(e & 255u);
            int s = (int)(e >> 8);
            float4 as4 = *(const float4*)(a_src + (size_t)s * NHEAD);
            float4 ad4 = adl[ln];
            float e0 = as4.x + ad4.x; e0 = fmaxf(e0, NEG_SLOPE * e0);
            float e1 = as4.y + ad4.y; e1 = fmaxf(e1, NEG_SLOPE * e1);
            float e2 = as4.z + ad4.z; e2 = fmaxf(e2, NEG_SLOPE * e2);
            float e3 = as4.w + ad4.w; e3 = fmaxf(e3, NEG_SLOPE * e3);
            ushort4 pw;
            pw.x = f2h(__expf(e0)); pw.y = f2h(__expf(e1));
            pw.z = f2h(__expf(e2)); pw.w = f2h(__expf(e3));
            int slot = cb + j + ln + 1;
            csr_src[slot] = s;
            *(ushort4*)(csr_w + (size_t)slot * 4) = pw;
            atomicAdd(&denom[ln][0], h2f(pw.x));
            atomicAdd(&denom[ln][1], h2f(pw.y));
            atomicAdd(&denom[ln][2], h2f(pw.z));
            atomicAdd(&denom[ln][3], h2f(pw.w));
        }
    } else {                            // fallback (oversized bucket)
        for (int i = lo + t; i < hi; i += 256) {
            unsigned e = ebuf[i];
            int ln = (int)(e & 255u);
            int s = (int)(e >> 8);
            int p = atomicAdd(&cur[ln], 1);
            float4 as4 = *(const float4*)(a_src + (size_t)s * NHEAD);
            float4 ad4 = adl[ln];
            float e0 = as4.x + ad4.x; e0 = fmaxf(e0, NEG_SLOPE * e0);
            float e1 = as4.y + ad4.y; e1 = fmaxf(e1, NEG_SLOPE * e1);
            float e2 = as4.z + ad4.z; e2 = fmaxf(e2, NEG_SLOPE * e2);
            float e3 = as4.w + ad4.w; e3 = fmaxf(e3, NEG_SLOPE * e3);
            ushort4 pw;
            pw.x = f2h(__expf(e0)); pw.y = f2h(__expf(e1));
            pw.z = f2h(__expf(e2)); pw.w = f2h(__expf(e3));
            int slot = cb + p + ln + 1;
            csr_src[slot] = s;
            *(ushort4*)(csr_w + (size_t)slot * 4) = pw;
            atomicAdd(&denom[ln][0], h2f(pw.x));
            atomicAdd(&denom[ln][1], h2f(pw.y));
            atomicAdd(&denom[ln][2], h2f(pw.z));
            atomicAdd(&denom[ln][3], h2f(pw.w));
        }
    }
    __syncthreads();
    if (t < ncnt) {
        float4 dv;
        dv.x = 1.0f / denom[t][0];
        dv.y = 1.0f / denom[t][1];
        dv.z = 1.0f / denom[t][2];
        dv.w = 1.0f / denom[t][3];
        *(float4*)(dinv + (size_t)(n0 + t) * NHEAD) = dv;
    }
}

// ------------- gather + weighted accumulate (weights precomputed) -----------
// One wave per node; lane l: head l>>4, channels 4*(l&15)..+3.
// Per edge: uniform csr_src + csr_w stream loads, one 512B wave gather, 4 FMA.
__global__ __launch_bounds__(256) void aggregate_kernel(
    const ushort* __restrict__ hb, const int* __restrict__ rowptr,
    const int* __restrict__ csr_src, const ushort* __restrict__ csr_w,
    const float* __restrict__ dinv, const float* __restrict__ bias,
    float* __restrict__ out, int N)
{
    int node = (int)((blockIdx.x * (size_t)blockDim.x + threadIdx.x) >> 6);
    int l = threadIdx.x & 63;
    if (node >= N) return;
    int start = rowptr[node];
    int end = rowptr[node + 1];
    int hd = l >> 4;

    float4 acc0 = make_float4(0.f, 0.f, 0.f, 0.f);
    float4 acc1 = make_float4(0.f, 0.f, 0.f, 0.f);
    float4 acc2 = make_float4(0.f, 0.f, 0.f, 0.f);
    float4 acc3 = make_float4(0.f, 0.f, 0.f, 0.f);

    int k = start;
    for (; k + 4 <= end; k += 4) {
        int sj0 = csr_src[k];
        int sj1 = csr_src[k + 1];
        int sj2 = csr_src[k + 2];
        int sj3 = csr_src[k + 3];
        uint2 wv0 = *(const uint2*)(csr_w + (size_t)(k + 0) * 4);
        uint2 wv1 = *(const uint2*)(csr_w + (size_t)(k + 1) * 4);
        uint2 wv2 = *(const uint2*)(csr_w + (size_t)(k + 2) * 4);
        uint2 wv3 = *(const uint2*)(csr_w + (size_t)(k + 3) * 4);
        ushort4 h0 = *(const ushort4*)(hb + ((size_t)sj0 << 8) + 4 * l);
        ushort4 h1 = *(const ushort4*)(hb + ((size_t)sj1 << 8) + 4 * l);
        ushort4 h2 = *(const ushort4*)(hb + ((size_t)sj2 << 8) + 4 * l);
        ushort4 h3 = *(const ushort4*)(hb + ((size_t)sj3 << 8) + 4 * l);
        unsigned d0 = (hd & 2) ? wv0.y : wv0.x;
        unsigned d1 = (hd & 2) ? wv1.y : wv1.x;
        unsigned d2 = (hd & 2) ? wv2.y : wv2.x;
        unsigned d3 = (hd & 2) ? wv3.y : wv3.x;
        float w0 = h2f((ushort)((hd & 1) ? (d0 >> 16) : (d0 & 0xFFFFu)));
        float w1 = h2f((ushort)((hd & 1) ? (d1 >> 16) : (d1 & 0xFFFFu)));
        float w2 = h2f((ushort)((hd & 1) ? (d2 >> 16) : (d2 & 0xFFFFu)));
        float w3 = h2f((ushort)((hd & 1) ? (d3 >> 16) : (d3 & 0xFFFFu)));
        acc0.x += w0 * bf2f(h0.x); acc0.y += w0 * bf2f(h0.y);
        acc0.z += w0 * bf2f(h0.z); acc0.w += w0 * bf2f(h0.w);
        acc1.x += w1 * bf2f(h1.x); acc1.y += w1 * bf2f(h1.y);
        acc1.z += w1 * bf2f(h1.z); acc1.w += w1 * bf2f(h1.w);
        acc2.x += w2 * bf2f(h2.x); acc2.y += w2 * bf2f(h2.y);
        acc2.z += w2 * bf2f(h2.z); acc2.w += w2 * bf2f(h2.w);
        acc3.x += w3 * bf2f(h3.x); acc3.y += w3 * bf2f(h3.y);
        acc3.z += w3 * bf2f(h3.z); acc3.w += w3 * bf2f(h3.w);
    }
    for (; k < end; ++k) {                       // tail (<=3 edges)
        int sj0 = csr_src[k];
        uint2 wv0 = *(const uint2*)(csr_w + (size_t)k * 4);
        ushort4 h0 = *(const ushort4*)(hb + ((size_t)sj0 << 8) + 4 * l);
        unsigned d0 = (hd & 2) ? wv0.y : wv0.x;
        float w0 = h2f((ushort)((hd & 1) ? (d0 >> 16) : (d0 & 0xFFFFu)));
        acc0.x += w0 * bf2f(h0.x); acc0.y += w0 * bf2f(h0.y);
        acc0.z += w0 * bf2f(h0.z); acc0.w += w0 * bf2f(h0.w);
    }

    float inv = dinv[(size_t)node * NHEAD + hd];
    float4 acc;
    acc.x = (acc0.x + acc1.x + acc2.x + acc3.x) * inv;
    acc.y = (acc0.y + acc1.y + acc2.y + acc3.y) * inv;
    acc.z = (acc0.z + acc1.z + acc2.z + acc3.z) * inv;
    acc.w = (acc0.w + acc1.w + acc2.w + acc3.w) * inv;

    // reduce over heads: lanes l, l^16, l^32, l^48 hold same channels
    #pragma unroll
    for (int off = 16; off < 64; off <<= 1) {
        acc.x += __shfl_xor(acc.x, off, 64);
        acc.y += __shfl_xor(acc.y, off, 64);
        acc.z += __shfl_xor(acc.z, off, 64);
        acc.w += __shfl_xor(acc.w, off, 64);
    }
    if (l < 16) {
        float4 b4 = *(const float4*)(bias + 4 * l);
        float4 o;
        o.x = acc.x * 0.25f + b4.x;
        o.y = acc.y * 0.25f + b4.y;
        o.z = acc.z * 0.25f + b4.z;
        o.w = acc.w * 0.25f + b4.w;
        o.x = (o.x > 0.f) ? o.x : (__expf(o.x) - 1.f);
        o.y = (o.y > 0.f) ? o.y : (__expf(o.y) - 1.f);
        o.z = (o.z > 0.f) ? o.z : (__expf(o.z) - 1.f);
        o.w = (o.w > 0.f) ? o.w : (__expf(o.w) - 1.f);
        *(float4*)(out + (size_t)node * CH + 4 * l) = o;
    }
}

extern "C" void kernel_launch(void* const* d_in, const int* in_sizes, int n_in,
                              void* d_out, int out_size, void* d_ws, size_t ws_size,
                              hipStream_t stream)
{
    const float* x         = (const float*)d_in[0];
    const int*   edge_idx  = (const int*)d_in[1];
    const float* W         = (const float*)d_in[2];
    const float* att_src   = (const float*)d_in[3];
    const float* att_dst   = (const float*)d_in[4];
    const float* bias      = (const float*)d_in[5];
    float* out = (float*)d_out;

    const int N = in_sizes[0] / IN_F;
    const int E = in_sizes[1] / 2;
    const int Etot = E + N;
    const int NB = (N + 255) >> 8;     // coarse buckets (assumes N <= 65536)
    const int* srcp = edge_idx;
    const int* dstp = edge_idx + E;

    char* ws = (char*)d_ws;
    size_t off = 0;
    ushort*  hb     = (ushort*)(ws + off);   off += align256((size_t)N * HC * sizeof(ushort));
    ushort*  Wt     = (ushort*)(ws + off);   off += align256((size_t)HC * IN_F * sizeof(ushort));
    float*   a_src  = (float*)(ws + off);    off += align256((size_t)N * NHEAD * sizeof(float));
    float*   a_dst  = (float*)(ws + off);    off += align256((size_t)N * NHEAD * sizeof(float));
    int*     ccnt   = (int*)(ws + off);      off += align256(256 * sizeof(int));
    int*     cur0   = (int*)(ws + off);      off += align256(256 * sizeof(int));
    unsigned* ebuf  = (unsigned*)(ws + off); off += align256((size_t)E * sizeof(unsigned));
    int*     rowptr = (int*)(ws + off);      off += align256(((size_t)N + 1) * sizeof(int));
    int*     csrs   = (int*)(ws + off);      off += align256((size_t)Etot * sizeof(int));
    ushort*  csr_w  = (ushort*)(ws + off);   off += align256((size_t)Etot * NHEAD * sizeof(ushort));
    float*   dinv   = (float*)(ws + off);    off += align256((size_t)N * NHEAD * sizeof(float));
    (void)ws_size; (void)n_in; (void)out_size;

    const int NTB = (N + 63) / 64;     // gemm tiles
    const int PBC = 208;               // fused count blocks (x2 = 416 slices)
    const int epbc = (E + 2 * PBC - 1) / (2 * PBC);
    const int PBS = (E + SC_EPB - 1) / SC_EPB;   // scatter blocks

    prep_kernel<<<IN_F * HC / 256, 256, 0, stream>>>(W, Wt, ccnt, cur0, rowptr, N, Etot);
    dim3 gg(NTB + PBC, 2);
    gemm_mfma_kernel<<<gg, 256, 0, stream>>>(x, Wt, att_src, att_dst, hb,
                                             a_src, a_dst, dstp, ccnt,
                                             E, epbc, NTB, NB, N);
    bucket_scatter<<<PBS, 256, 0, stream>>>(srcp, dstp, ccnt, cur0, ebuf, E);
    csr_build<<<NB, 256, 0, stream>>>(ebuf, ccnt, a_src, a_dst,
                                      rowptr, csrs, csr_w, dinv, N, NB);
    aggregate_kernel<<<((size_t)N * 64 + 255) / 256, 256, 0, stream>>>(
        hb, rowptr, csrs, csr_w, dinv, bias, out, N);
}

// Round 9
// 207.314 us; speedup vs baseline: 1.1201x; 1.1201x over previous
//
#include <hip/hip_runtime.h>

#define NEG_SLOPE 0.2f
static constexpr int IN_F = 128;   // input feature dim
static constexpr int NHEAD = 4;
static constexpr int CH = 64;      // channels per head
static constexpr int HC = 256;     // NHEAD*CH
static constexpr int SC_EPB = 2000;  // edges per scatter block
static constexpr int CB_CAP = 6144;  // csr_build LDS sort capacity

static __host__ size_t align256(size_t v) { return (v + 255) & ~((size_t)255); }

__device__ inline ushort f2bf(float f) {          // round-to-nearest-even fp32->bf16
    unsigned u = __float_as_uint(f);
    unsigned r = u + 0x7FFFu + ((u >> 16) & 1u);
    return (ushort)(r >> 16);
}
__device__ inline float bf2f(ushort s) { return __uint_as_float(((unsigned)s) << 16); }

typedef short s16x8 __attribute__((ext_vector_type(8)));    // 8 bf16 = 4 VGPR
typedef float f32x16 __attribute__((ext_vector_type(16)));  // 32x32 accumulator

// ---- prep: Wt[n][k] = bf16(W[k][n]) + zero counters + rowptr[N] ------------
__global__ __launch_bounds__(256) void prep_kernel(
    const float* __restrict__ W, ushort* __restrict__ Wt,
    int* __restrict__ ccnt, int* __restrict__ cur0,
    int* __restrict__ rowptr, int N, int Etot)
{
    int f = blockIdx.x * 256 + threadIdx.x;     // 32768 elements
    int k = f >> 8;                             // 0..127
    int n = f & 255;                            // 0..255
    Wt[n * IN_F + k] = f2bf(W[(size_t)k * HC + n]);
    if (blockIdx.x == 0) {
        ccnt[threadIdx.x] = 0;
        cur0[threadIdx.x] = 0;
        if (threadIdx.x == 0) rowptr[N] = Etot;
    }
}

// ---- MFMA GEMM (2 heads/block) + fused edge bucket-count -------------------
__global__ __launch_bounds__(256) void gemm_mfma_kernel(
    const float* __restrict__ x, const ushort* __restrict__ Wt,
    const float* __restrict__ att_src, const float* __restrict__ att_dst,
    ushort* __restrict__ hb, float* __restrict__ a_src, float* __restrict__ a_dst,
    const int* __restrict__ dst, int* __restrict__ coarse_cnt,
    int E, int epb, int NTB, int NB, int N)
{
    constexpr int LDK = 136;            // padded K stride (ushort elems)
    __shared__ ushort As[64 * LDK];     // x tile [m][k] bf16
    __shared__ ushort Bs[128 * LDK];    // Wt tile [n][k] bf16
    ushort* Hs = As;                    // h-tile aliases As after MFMA

    const int t = threadIdx.x;

    if (blockIdx.x >= NTB) {            // ---- bucket-count role ----
        int* hist = (int*)As;
        hist[t] = 0;
        __syncthreads();
        int slice = (blockIdx.x - NTB) * 2 + blockIdx.y;
        int lo = slice * epb;
        int hi = min(E, lo + epb);
        for (int i = lo + t; i < hi; i += 256)
            atomicAdd(&hist[((unsigned)dst[i]) >> 8], 1);
        __syncthreads();
        if (t < NB && hist[t]) atomicAdd(&coarse_cnt[t], hist[t]);
        return;
    }

    const int m0 = blockIdx.x * 64;
    const int n0 = blockIdx.y * 128;    // col offset in h (2 heads)

    #pragma unroll
    for (int u = 0; u < 8; ++u) {
        int f = t + 256 * u;
        int r = f >> 5;
        int k4 = (f & 31) * 4;
        int row = m0 + r;
        float4 v = make_float4(0.f, 0.f, 0.f, 0.f);
        if (row < N) v = *(const float4*)(x + (size_t)row * IN_F + k4);
        ushort4 o;
        o.x = f2bf(v.x); o.y = f2bf(v.y); o.z = f2bf(v.z); o.w = f2bf(v.w);
        *(ushort4*)&As[r * LDK + k4] = o;
    }
    #pragma unroll
    for (int u = 0; u < 8; ++u) {
        int f = t + 256 * u;
        int n = f >> 4;
        int k8 = (f & 15) * 8;
        uint4 v = *(const uint4*)(Wt + (size_t)(n0 + n) * IN_F + k8);
        *(uint4*)&Bs[n * LDK + k8] = v;
    }
    __syncthreads();

    const int w = t >> 6;
    const int lane = t & 63;
    const int mrow = 32 * (w >> 1) + (lane & 31);
    const int nbase = 64 * (w & 1) + (lane & 31);
    const int kq = (lane >> 5) * 8;

    f32x16 acc0 = {}, acc1 = {};
    #pragma unroll
    for (int s = 0; s < 8; ++s) {
        s16x8 af = *(const s16x8*)&As[mrow * LDK + 16 * s + kq];
        s16x8 b0 = *(const s16x8*)&Bs[nbase * LDK + 16 * s + kq];
        s16x8 b1 = *(const s16x8*)&Bs[(nbase + 32) * LDK + 16 * s + kq];
        acc0 = __builtin_amdgcn_mfma_f32_32x32x16_bf16(af, b0, acc0, 0, 0, 0);
        acc1 = __builtin_amdgcn_mfma_f32_32x32x16_bf16(af, b1, acc1, 0, 0, 0);
    }
    __syncthreads();

    {
        int rbase = 4 * (lane >> 5) + 32 * (w >> 1);
        int c0 = 64 * (w & 1) + (lane & 31);
        #pragma unroll
        for (int r = 0; r < 16; ++r) {
            int rowL = rbase + (r & 3) + 8 * (r >> 2);
            Hs[rowL * LDK + c0]      = f2bf(acc0[r]);
            Hs[rowL * LDK + c0 + 32] = f2bf(acc1[r]);
        }
    }
    __syncthreads();

    {
        int r2 = t >> 2;
        int q = t & 3;
        int row = m0 + r2;
        uint4 p0 = *(const uint4*)&Hs[r2 * LDK + 32 * q];
        uint4 p1 = *(const uint4*)&Hs[r2 * LDK + 32 * q + 8];
        uint4 p2 = *(const uint4*)&Hs[r2 * LDK + 32 * q + 16];
        uint4 p3 = *(const uint4*)&Hs[r2 * LDK + 32 * q + 24];
        if (row < N) {
            ushort* dsth = hb + (size_t)row * HC + n0 + 32 * q;
            *(uint4*)(dsth)      = p0;
            *(uint4*)(dsth + 8)  = p1;
            *(uint4*)(dsth + 16) = p2;
            *(uint4*)(dsth + 24) = p3;
        }
        int hq = 2 * blockIdx.y + (q >> 1);
        int cb = (q & 1) * 32;
        const float* asp = att_src + hq * CH + cb;
        const float* adp = att_dst + hq * CH + cb;
        unsigned uu[16] = { p0.x, p0.y, p0.z, p0.w, p1.x, p1.y, p1.z, p1.w,
                            p2.x, p2.y, p2.z, p2.w, p3.x, p3.y, p3.z, p3.w };
        float ps = 0.f, pd = 0.f;
        #pragma unroll
        for (int i = 0; i < 16; ++i) {
            float lo = bf2f((ushort)(uu[i] & 0xFFFFu));
            float hi = bf2f((ushort)(uu[i] >> 16));
            ps += lo * asp[2 * i] + hi * asp[2 * i + 1];
            pd += lo * adp[2 * i] + hi * adp[2 * i + 1];
        }
        ps += __shfl_xor(ps, 1, 64);
        pd += __shfl_xor(pd, 1, 64);
        if ((q & 1) == 0 && row < N) {
            a_src[(size_t)row * NHEAD + hq] = ps;
            a_dst[(size_t)row * NHEAD + hq] = pd;
        }
    }
}

// pass 3: scatter edges into bucket regions via block-local LDS counting sort.
// Each block re-derives ebase by scanning ccnt. Packed: (src << 8) | (dst&255)
__global__ __launch_bounds__(256) void bucket_scatter(
    const int* __restrict__ src, const int* __restrict__ dst,
    const int* __restrict__ ccnt, int* __restrict__ cur0,
    unsigned* __restrict__ ebuf, int E)
{
    __shared__ int eb[256];             // exclusive base per bucket
    __shared__ int hist[256];
    __shared__ int lbase[256];
    __shared__ int gbase[256];
    __shared__ int cur[256];
    __shared__ unsigned sbuf[SC_EPB + 48];
    __shared__ unsigned char tb[SC_EPB + 48];
    int t = threadIdx.x;
    int cv = ccnt[t];
    eb[t] = cv;
    __syncthreads();
    #pragma unroll
    for (int off = 1; off < 256; off <<= 1) {
        int a = eb[t];
        int b = (t >= off) ? eb[t - off] : 0;
        __syncthreads();
        eb[t] = a + b;
        __syncthreads();
    }
    int myebase = eb[t] - cv;
    __syncthreads();
    eb[t] = myebase;

    int lo = blockIdx.x * SC_EPB;
    int hi = min(E, lo + SC_EPB);
    int cnt = hi - lo;
    hist[t] = 0;
    __syncthreads();
    unsigned pk[8]; int bk[8];
    #pragma unroll
    for (int u = 0; u < 8; ++u) {
        int i = lo + t + 256 * u;
        bk[u] = -1;
        if (i < hi) {
            unsigned d = (unsigned)dst[i];
            bk[u] = (int)(d >> 8);
            pk[u] = (((unsigned)src[i]) << 8) | (d & 255u);
            atomicAdd(&hist[bk[u]], 1);
        }
    }
    __syncthreads();
    int v = hist[t];
    lbase[t] = v;
    __syncthreads();
    #pragma unroll
    for (int off = 1; off < 256; off <<= 1) {
        int a = lbase[t];
        int b = (t >= off) ? lbase[t - off] : 0;
        __syncthreads();
        lbase[t] = a + b;
        __syncthreads();
    }
    int excl = lbase[t] - v;
    if (v) gbase[t] = eb[t] + atomicAdd(&cur0[t], v);   // reserve global run
    __syncthreads();
    lbase[t] = excl;
    cur[t] = excl;
    __syncthreads();
    #pragma unroll
    for (int u = 0; u < 8; ++u) {
        if (bk[u] >= 0) {
            int p = atomicAdd(&cur[bk[u]], 1);
            sbuf[p] = pk[u];
            tb[p] = (unsigned char)bk[u];
        }
    }
    __syncthreads();
    for (int j = t; j < cnt; j += 256) {
        int b = tb[j];
        ebuf[gbase[b] + j - lbase[b]] = sbuf[j];
    }
}

// pass 4: per-bucket CSR finalize with LDS sort -> coalesced final writes.
// Self loop goes first in each node's segment. ebase derived via ccnt scan.
__global__ __launch_bounds__(256) void csr_build(
    const unsigned* __restrict__ ebuf, const int* __restrict__ ccnt,
    int* __restrict__ rowptr, int* __restrict__ csr_src, int N)
{
    __shared__ int scn[256];
    __shared__ int hist[256];
    __shared__ int cur[256];
    __shared__ unsigned srt[CB_CAP];
    int b = blockIdx.x;
    int t = threadIdx.x;
    int cv = ccnt[t];
    scn[t] = cv;
    __syncthreads();
    #pragma unroll
    for (int off = 1; off < 256; off <<= 1) {
        int a = scn[t];
        int bb = (t >= off) ? scn[t - off] : 0;
        __syncthreads();
        scn[t] = a + bb;
        __syncthreads();
    }
    int lo = (b == 0) ? 0 : scn[b - 1];
    int hi = scn[b];
    __syncthreads();

    int n0 = b << 8;
    int ncnt = min(256, N - n0);
    int cnt = hi - lo;
    int cb = lo + n0;                   // global csr base (n0 = self loops before)
    hist[t] = 0;
    __syncthreads();
    for (int i = lo + t; i < hi; i += 256)
        atomicAdd(&hist[ebuf[i] & 255u], 1);
    __syncthreads();
    int v = hist[t];
    scn[t] = v;
    __syncthreads();
    #pragma unroll
    for (int off = 1; off < 256; off <<= 1) {
        int a = scn[t];
        int bb = (t >= off) ? scn[t - off] : 0;
        __syncthreads();
        scn[t] = a + bb;
        __syncthreads();
    }
    int excl = scn[t] - v;
    if (t < ncnt) {
        int segstart = cb + excl + t;   // +t = self loops of prior nodes
        rowptr[n0 + t] = segstart;
        csr_src[segstart] = n0 + t;     // self loop first
    }
    cur[t] = excl;
    __syncthreads();
    if (cnt <= CB_CAP) {
        for (int i = lo + t; i < hi; i += 256) {
            unsigned e = ebuf[i];
            int p = atomicAdd(&cur[e & 255u], 1);
            srt[p] = e;
        }
        __syncthreads();
        for (int j = t; j < cnt; j += 256) {
            unsigned e = srt[j];
            csr_src[cb + j + (int)(e & 255u) + 1] = (int)(e >> 8);
        }
    } else {                            // fallback (oversized bucket)
        for (int i = lo + t; i < hi; i += 256) {
            unsigned e = ebuf[i];
            int ln = (int)(e & 255u);
            int p = atomicAdd(&cur[ln], 1);
            csr_src[cb + p + ln + 1] = (int)(e >> 8);
        }
    }
}

// ------------- single-pass softmax aggregate, 2 waves per node --------------
// Latency-bound gather loop: halve each wave's serial edge chain by splitting
// a node's edge list across 2 waves; combine partials via LDS.
// Block = 4 waves = 2 nodes. Lane l: head l>>4, channels 4*(l&15)..+3.
__global__ __launch_bounds__(256) void aggregate_kernel(
    const ushort* __restrict__ hb, const float* __restrict__ a_src,
    const float* __restrict__ a_dst, const int* __restrict__ rowptr,
    const int* __restrict__ csr_src, const float* __restrict__ bias,
    float* __restrict__ out, int N)
{
    __shared__ float accsm[2][64][4];
    __shared__ float ssm[2][4];
    int t = threadIdx.x;
    int w = t >> 6;             // wave 0..3
    int half = w & 1;           // which half of the edge list
    int lnode = w >> 1;         // local node 0/1
    int node = blockIdx.x * 2 + lnode;
    int l = t & 63;
    int hd = l >> 4;

    bool active = node < N;
    int start = 0, end = 0;
    float adh = 0.f;
    if (active) {
        start = rowptr[node];
        end = rowptr[node + 1];
        adh = a_dst[(size_t)node * NHEAD + hd];
    }
    int hdeg = (end - start + 1) >> 1;
    int mylo = start + half * hdeg;
    int myhi = half ? end : (start + hdeg);

    float4 acc0 = make_float4(0.f, 0.f, 0.f, 0.f);
    float4 acc1 = make_float4(0.f, 0.f, 0.f, 0.f);
    float4 acc2 = make_float4(0.f, 0.f, 0.f, 0.f);
    float4 acc3 = make_float4(0.f, 0.f, 0.f, 0.f);
    float s0 = 0.f, s1 = 0.f, s2 = 0.f, s3 = 0.f;

    int k = mylo;
    for (; k + 4 <= myhi; k += 4) {
        int sj0 = csr_src[k];
        int sj1 = csr_src[k + 1];
        int sj2 = csr_src[k + 2];
        int sj3 = csr_src[k + 3];
        float a0 = a_src[(size_t)sj0 * NHEAD + hd];
        float a1 = a_src[(size_t)sj1 * NHEAD + hd];
        float a2 = a_src[(size_t)sj2 * NHEAD + hd];
        float a3 = a_src[(size_t)sj3 * NHEAD + hd];
        ushort4 h0 = *(const ushort4*)(hb + ((size_t)sj0 << 8) + 4 * l);
        ushort4 h1 = *(const ushort4*)(hb + ((size_t)sj1 << 8) + 4 * l);
        ushort4 h2 = *(const ushort4*)(hb + ((size_t)sj2 << 8) + 4 * l);
        ushort4 h3 = *(const ushort4*)(hb + ((size_t)sj3 << 8) + 4 * l);
        float e0 = a0 + adh; e0 = fmaxf(e0, NEG_SLOPE * e0); float w0 = __expf(e0);
        float e1 = a1 + adh; e1 = fmaxf(e1, NEG_SLOPE * e1); float w1 = __expf(e1);
        float e2 = a2 + adh; e2 = fmaxf(e2, NEG_SLOPE * e2); float w2 = __expf(e2);
        float e3 = a3 + adh; e3 = fmaxf(e3, NEG_SLOPE * e3); float w3 = __expf(e3);
        s0 += w0; s1 += w1; s2 += w2; s3 += w3;
        acc0.x += w0 * bf2f(h0.x); acc0.y += w0 * bf2f(h0.y);
        acc0.z += w0 * bf2f(h0.z); acc0.w += w0 * bf2f(h0.w);
        acc1.x += w1 * bf2f(h1.x); acc1.y += w1 * bf2f(h1.y);
        acc1.z += w1 * bf2f(h1.z); acc1.w += w1 * bf2f(h1.w);
        acc2.x += w2 * bf2f(h2.x); acc2.y += w2 * bf2f(h2.y);
        acc2.z += w2 * bf2f(h2.z); acc2.w += w2 * bf2f(h2.w);
        acc3.x += w3 * bf2f(h3.x); acc3.y += w3 * bf2f(h3.y);
        acc3.z += w3 * bf2f(h3.z); acc3.w += w3 * bf2f(h3.w);
    }
    for (; k < myhi; ++k) {                      // tail (<=3 edges)
        int sj0 = csr_src[k];
        float a0 = a_src[(size_t)sj0 * NHEAD + hd];
        ushort4 h0 = *(const ushort4*)(hb + ((size_t)sj0 << 8) + 4 * l);
        float e0 = a0 + adh; e0 = fmaxf(e0, NEG_SLOPE * e0);
        float w0 = __expf(e0);
        s0 += w0;
        acc0.x += w0 * bf2f(h0.x); acc0.y += w0 * bf2f(h0.y);
        acc0.z += w0 * bf2f(h0.z); acc0.w += w0 * bf2f(h0.w);
    }

    float4 acc;
    acc.x = acc0.x + acc1.x + acc2.x + acc3.x;
    acc.y = acc0.y + acc1.y + acc2.y + acc3.y;
    acc.z = acc0.z + acc1.z + acc2.z + acc3.z;
    acc.w = acc0.w + acc1.w + acc2.w + acc3.w;
    float sloc = s0 + s1 + s2 + s3;

    if (half == 1) {                    // publish partial
        *(float4*)&accsm[lnode][l][0] = acc;
        if ((l & 15) == 0) ssm[lnode][hd] = sloc;
    }
    __syncthreads();
    if (half == 0 && active) {
        float4 o2 = *(const float4*)&accsm[lnode][l][0];
        acc.x += o2.x; acc.y += o2.y; acc.z += o2.z; acc.w += o2.w;
        float inv = 1.0f / (sloc + ssm[lnode][hd]);
        acc.x *= inv; acc.y *= inv; acc.z *= inv; acc.w *= inv;
        // reduce over heads: lanes l, l^16, l^32, l^48 hold same channels
        #pragma unroll
        for (int off = 16; off < 64; off <<= 1) {
            acc.x += __shfl_xor(acc.x, off, 64);
            acc.y += __shfl_xor(acc.y, off, 64);
            acc.z += __shfl_xor(acc.z, off, 64);
            acc.w += __shfl_xor(acc.w, off, 64);
        }
        if (l < 16) {
            float4 b4 = *(const float4*)(bias + 4 * l);
            float4 o;
            o.x = acc.x * 0.25f + b4.x;
            o.y = acc.y * 0.25f + b4.y;
            o.z = acc.z * 0.25f + b4.z;
            o.w = acc.w * 0.25f + b4.w;
            o.x = (o.x > 0.f) ? o.x : (__expf(o.x) - 1.f);
            o.y = (o.y > 0.f) ? o.y : (__expf(o.y) - 1.f);
            o.z = (o.z > 0.f) ? o.z : (__expf(o.z) - 1.f);
            o.w = (o.w > 0.f) ? o.w : (__expf(o.w) - 1.f);
            *(float4*)(out + (size_t)node * CH + 4 * l) = o;
        }
    }
}

extern "C" void kernel_launch(void* const* d_in, const int* in_sizes, int n_in,
                              void* d_out, int out_size, void* d_ws, size_t ws_size,
                              hipStream_t stream)
{
    const float* x         = (const float*)d_in[0];
    const int*   edge_idx  = (const int*)d_in[1];
    const float* W         = (const float*)d_in[2];
    const float* att_src   = (const float*)d_in[3];
    const float* att_dst   = (const float*)d_in[4];
    const float* bias      = (const float*)d_in[5];
    float* out = (float*)d_out;

    const int N = in_sizes[0] / IN_F;
    const int E = in_sizes[1] / 2;
    const int Etot = E + N;
    const int NB = (N + 255) >> 8;     // coarse buckets (assumes N <= 65536)
    const int* srcp = edge_idx;
    const int* dstp = edge_idx + E;

    char* ws = (char*)d_ws;
    size_t off = 0;
    ushort*  hb     = (ushort*)(ws + off);   off += align256((size_t)N * HC * sizeof(ushort));
    ushort*  Wt     = (ushort*)(ws + off);   off += align256((size_t)HC * IN_F * sizeof(ushort));
    float*   a_src  = (float*)(ws + off);    off += align256((size_t)N * NHEAD * sizeof(float));
    float*   a_dst  = (float*)(ws + off);    off += align256((size_t)N * NHEAD * sizeof(float));
    int*     ccnt   = (int*)(ws + off);      off += align256(256 * sizeof(int));
    int*     cur0   = (int*)(ws + off);      off += align256(256 * sizeof(int));
    unsigned* ebuf  = (unsigned*)(ws + off); off += align256((size_t)E * sizeof(unsigned));
    int*     rowptr = (int*)(ws + off);      off += align256(((size_t)N + 1) * sizeof(int));
    int*     csrs   = (int*)(ws + off);      off += align256((size_t)Etot * sizeof(int));
    (void)ws_size; (void)n_in; (void)out_size;

    const int NTB = (N + 63) / 64;     // gemm tiles
    const int PBC = 208;               // fused count blocks (x2 = 416 slices)
    const int epbc = (E + 2 * PBC - 1) / (2 * PBC);
    const int PBS = (E + SC_EPB - 1) / SC_EPB;   // scatter blocks

    prep_kernel<<<IN_F * HC / 256, 256, 0, stream>>>(W, Wt, ccnt, cur0, rowptr, N, Etot);
    dim3 gg(NTB + PBC, 2);
    gemm_mfma_kernel<<<gg, 256, 0, stream>>>(x, Wt, att_src, att_dst, hb,
                                             a_src, a_dst, dstp, ccnt,
                                             E, epbc, NTB, NB, N);
    bucket_scatter<<<PBS, 256, 0, stream>>>(srcp, dstp, ccnt, cur0, ebuf, E);
    csr_build<<<NB, 256, 0, stream>>>(ebuf, ccnt, rowptr, csrs, N);
    aggregate_kernel<<<((N + 1) / 2), 256, 0, stream>>>(
        hb, a_src, a_dst, rowptr, csrs, bias, out, N);
}

// Round 10
// 200.954 us; speedup vs baseline: 1.1556x; 1.0317x over previous
//
#include <hip/hip_runtime.h>

#define NEG_SLOPE 0.2f
static constexpr int IN_F = 128;   // input feature dim
static constexpr int NHEAD = 4;
static constexpr int CH = 64;      // channels per head
static constexpr int HC = 256;     // NHEAD*CH
static constexpr int SC_EPB = 2000;  // edges per scatter block
static constexpr int CB_CAP = 6144;  // csr_build LDS sort capacity
static constexpr int CPAD = 16;      // counter pad: 1 counter per 64B line

static __host__ size_t align256(size_t v) { return (v + 255) & ~((size_t)255); }

__device__ inline ushort f2bf(float f) {          // round-to-nearest-even fp32->bf16
    unsigned u = __float_as_uint(f);
    unsigned r = u + 0x7FFFu + ((u >> 16) & 1u);
    return (ushort)(r >> 16);
}
__device__ inline float bf2f(ushort s) { return __uint_as_float(((unsigned)s) << 16); }

typedef short s16x8 __attribute__((ext_vector_type(8)));    // 8 bf16 = 4 VGPR
typedef float f32x16 __attribute__((ext_vector_type(16)));  // 32x32 accumulator

// ---- prep: Wt[n][k] = bf16(W[k][n]) + zero padded counters + rowptr[N] -----
__global__ __launch_bounds__(256) void prep_kernel(
    const float* __restrict__ W, ushort* __restrict__ Wt,
    int* __restrict__ ccnt, int* __restrict__ cur0,
    int* __restrict__ rowptr, int N, int Etot)
{
    int f = blockIdx.x * 256 + threadIdx.x;     // 32768 elements
    int k = f >> 8;                             // 0..127
    int n = f & 255;                            // 0..255
    Wt[n * IN_F + k] = f2bf(W[(size_t)k * HC + n]);
    if (f < 256 * CPAD) { ccnt[f] = 0; cur0[f] = 0; }
    if (f == 0) rowptr[N] = Etot;
}

// ---- MFMA GEMM (2 heads/block) + fused edge bucket-count -------------------
__global__ __launch_bounds__(256) void gemm_mfma_kernel(
    const float* __restrict__ x, const ushort* __restrict__ Wt,
    const float* __restrict__ att_src, const float* __restrict__ att_dst,
    ushort* __restrict__ hb, float* __restrict__ a_src, float* __restrict__ a_dst,
    const int* __restrict__ dst, int* __restrict__ coarse_cnt,
    int E, int epb, int NTB, int NB, int N)
{
    constexpr int LDK = 136;            // padded K stride (ushort elems)
    __shared__ ushort As[64 * LDK];     // x tile [m][k] bf16
    __shared__ ushort Bs[128 * LDK];    // Wt tile [n][k] bf16
    ushort* Hs = As;                    // h-tile aliases As after MFMA

    const int t = threadIdx.x;

    if (blockIdx.x >= NTB) {            // ---- bucket-count role ----
        int* hist = (int*)As;
        hist[t] = 0;
        __syncthreads();
        int slice = (blockIdx.x - NTB) * 2 + blockIdx.y;
        int lo = slice * epb;
        int hi = min(E, lo + epb);
        for (int i = lo + t; i < hi; i += 256)
            atomicAdd(&hist[((unsigned)dst[i]) >> 8], 1);
        __syncthreads();
        if (t < NB && hist[t]) atomicAdd(&coarse_cnt[t * CPAD], hist[t]);
        return;
    }

    const int m0 = blockIdx.x * 64;
    const int n0 = blockIdx.y * 128;    // col offset in h (2 heads)

    #pragma unroll
    for (int u = 0; u < 8; ++u) {
        int f = t + 256 * u;
        int r = f >> 5;
        int k4 = (f & 31) * 4;
        int row = m0 + r;
        float4 v = make_float4(0.f, 0.f, 0.f, 0.f);
        if (row < N) v = *(const float4*)(x + (size_t)row * IN_F + k4);
        ushort4 o;
        o.x = f2bf(v.x); o.y = f2bf(v.y); o.z = f2bf(v.z); o.w = f2bf(v.w);
        *(ushort4*)&As[r * LDK + k4] = o;
    }
    #pragma unroll
    for (int u = 0; u < 8; ++u) {
        int f = t + 256 * u;
        int n = f >> 4;
        int k8 = (f & 15) * 8;
        uint4 v = *(const uint4*)(Wt + (size_t)(n0 + n) * IN_F + k8);
        *(uint4*)&Bs[n * LDK + k8] = v;
    }
    __syncthreads();

    const int w = t >> 6;
    const int lane = t & 63;
    const int mrow = 32 * (w >> 1) + (lane & 31);
    const int nbase = 64 * (w & 1) + (lane & 31);
    const int kq = (lane >> 5) * 8;

    f32x16 acc0 = {}, acc1 = {};
    #pragma unroll
    for (int s = 0; s < 8; ++s) {
        s16x8 af = *(const s16x8*)&As[mrow * LDK + 16 * s + kq];
        s16x8 b0 = *(const s16x8*)&Bs[nbase * LDK + 16 * s + kq];
        s16x8 b1 = *(const s16x8*)&Bs[(nbase + 32) * LDK + 16 * s + kq];
        acc0 = __builtin_amdgcn_mfma_f32_32x32x16_bf16(af, b0, acc0, 0, 0, 0);
        acc1 = __builtin_amdgcn_mfma_f32_32x32x16_bf16(af, b1, acc1, 0, 0, 0);
    }
    __syncthreads();

    {
        int rbase = 4 * (lane >> 5) + 32 * (w >> 1);
        int c0 = 64 * (w & 1) + (lane & 31);
        #pragma unroll
        for (int r = 0; r < 16; ++r) {
            int rowL = rbase + (r & 3) + 8 * (r >> 2);
            Hs[rowL * LDK + c0]      = f2bf(acc0[r]);
            Hs[rowL * LDK + c0 + 32] = f2bf(acc1[r]);
        }
    }
    __syncthreads();

    {
        int r2 = t >> 2;
        int q = t & 3;
        int row = m0 + r2;
        uint4 p0 = *(const uint4*)&Hs[r2 * LDK + 32 * q];
        uint4 p1 = *(const uint4*)&Hs[r2 * LDK + 32 * q + 8];
        uint4 p2 = *(const uint4*)&Hs[r2 * LDK + 32 * q + 16];
        uint4 p3 = *(const uint4*)&Hs[r2 * LDK + 32 * q + 24];
        if (row < N) {
            ushort* dsth = hb + (size_t)row * HC + n0 + 32 * q;
            *(uint4*)(dsth)      = p0;
            *(uint4*)(dsth + 8)  = p1;
            *(uint4*)(dsth + 16) = p2;
            *(uint4*)(dsth + 24) = p3;
        }
        int hq = 2 * blockIdx.y + (q >> 1);
        int cb = (q & 1) * 32;
        const float* asp = att_src + hq * CH + cb;
        const float* adp = att_dst + hq * CH + cb;
        unsigned uu[16] = { p0.x, p0.y, p0.z, p0.w, p1.x, p1.y, p1.z, p1.w,
                            p2.x, p2.y, p2.z, p2.w, p3.x, p3.y, p3.z, p3.w };
        float ps = 0.f, pd = 0.f;
        #pragma unroll
        for (int i = 0; i < 16; ++i) {
            float lo = bf2f((ushort)(uu[i] & 0xFFFFu));
            float hi = bf2f((ushort)(uu[i] >> 16));
            ps += lo * asp[2 * i] + hi * asp[2 * i + 1];
            pd += lo * adp[2 * i] + hi * adp[2 * i + 1];
        }
        ps += __shfl_xor(ps, 1, 64);
        pd += __shfl_xor(pd, 1, 64);
        if ((q & 1) == 0 && row < N) {
            a_src[(size_t)row * NHEAD + hq] = ps;
            a_dst[(size_t)row * NHEAD + hq] = pd;
        }
    }
}

// pass 3: scatter edges into bucket regions via block-local LDS counting sort.
// Each block re-derives ebase by scanning ccnt. Packed: (src << 8) | (dst&255)
__global__ __launch_bounds__(256) void bucket_scatter(
    const int* __restrict__ src, const int* __restrict__ dst,
    const int* __restrict__ ccnt, int* __restrict__ cur0,
    unsigned* __restrict__ ebuf, int E)
{
    __shared__ int eb[256];             // exclusive base per bucket
    __shared__ int hist[256];
    __shared__ int lbase[256];
    __shared__ int gbase[256];
    __shared__ int cur[256];
    __shared__ unsigned sbuf[SC_EPB + 48];
    __shared__ unsigned char tb[SC_EPB + 48];
    int t = threadIdx.x;
    int cv = ccnt[t * CPAD];
    eb[t] = cv;
    __syncthreads();
    #pragma unroll
    for (int off = 1; off < 256; off <<= 1) {
        int a = eb[t];
        int b = (t >= off) ? eb[t - off] : 0;
        __syncthreads();
        eb[t] = a + b;
        __syncthreads();
    }
    int myebase = eb[t] - cv;
    __syncthreads();
    eb[t] = myebase;

    int lo = blockIdx.x * SC_EPB;
    int hi = min(E, lo + SC_EPB);
    int cnt = hi - lo;
    hist[t] = 0;
    __syncthreads();
    unsigned pk[8]; int bk[8];
    #pragma unroll
    for (int u = 0; u < 8; ++u) {
        int i = lo + t + 256 * u;
        bk[u] = -1;
        if (i < hi) {
            unsigned d = (unsigned)dst[i];
            bk[u] = (int)(d >> 8);
            pk[u] = (((unsigned)src[i]) << 8) | (d & 255u);
            atomicAdd(&hist[bk[u]], 1);
        }
    }
    __syncthreads();
    int v = hist[t];
    lbase[t] = v;
    __syncthreads();
    #pragma unroll
    for (int off = 1; off < 256; off <<= 1) {
        int a = lbase[t];
        int b = (t >= off) ? lbase[t - off] : 0;
        __syncthreads();
        lbase[t] = a + b;
        __syncthreads();
    }
    int excl = lbase[t] - v;
    if (v) gbase[t] = eb[t] + atomicAdd(&cur0[t * CPAD], v);  // reserve run
    __syncthreads();
    lbase[t] = excl;
    cur[t] = excl;
    __syncthreads();
    #pragma unroll
    for (int u = 0; u < 8; ++u) {
        if (bk[u] >= 0) {
            int p = atomicAdd(&cur[bk[u]], 1);
            sbuf[p] = pk[u];
            tb[p] = (unsigned char)bk[u];
        }
    }
    __syncthreads();
    for (int j = t; j < cnt; j += 256) {
        int b = tb[j];
        ebuf[gbase[b] + j - lbase[b]] = sbuf[j];
    }
}

// pass 4: per-bucket CSR finalize with LDS sort -> coalesced final writes.
// Self loop goes first in each node's segment. ebase derived via ccnt scan.
__global__ __launch_bounds__(256) void csr_build(
    const unsigned* __restrict__ ebuf, const int* __restrict__ ccnt,
    int* __restrict__ rowptr, int* __restrict__ csr_src, int N)
{
    __shared__ int scn[256];
    __shared__ int hist[256];
    __shared__ int cur[256];
    __shared__ unsigned srt[CB_CAP];
    int b = blockIdx.x;
    int t = threadIdx.x;
    int cv = ccnt[t * CPAD];
    scn[t] = cv;
    __syncthreads();
    #pragma unroll
    for (int off = 1; off < 256; off <<= 1) {
        int a = scn[t];
        int bb = (t >= off) ? scn[t - off] : 0;
        __syncthreads();
        scn[t] = a + bb;
        __syncthreads();
    }
    int lo = (b == 0) ? 0 : scn[b - 1];
    int hi = scn[b];
    __syncthreads();

    int n0 = b << 8;
    int ncnt = min(256, N - n0);
    int cnt = hi - lo;
    int cb = lo + n0;                   // global csr base (n0 = self loops before)
    hist[t] = 0;
    __syncthreads();
    for (int i = lo + t; i < hi; i += 256)
        atomicAdd(&hist[ebuf[i] & 255u], 1);
    __syncthreads();
    int v = hist[t];
    scn[t] = v;
    __syncthreads();
    #pragma unroll
    for (int off = 1; off < 256; off <<= 1) {
        int a = scn[t];
        int bb = (t >= off) ? scn[t - off] : 0;
        __syncthreads();
        scn[t] = a + bb;
        __syncthreads();
    }
    int excl = scn[t] - v;
    if (t < ncnt) {
        int segstart = cb + excl + t;   // +t = self loops of prior nodes
        rowptr[n0 + t] = segstart;
        csr_src[segstart] = n0 + t;     // self loop first
    }
    cur[t] = excl;
    __syncthreads();
    if (cnt <= CB_CAP) {
        for (int i = lo + t; i < hi; i += 256) {
            unsigned e = ebuf[i];
            int p = atomicAdd(&cur[e & 255u], 1);
            srt[p] = e;
        }
        __syncthreads();
        for (int j = t; j < cnt; j += 256) {
            unsigned e = srt[j];
            csr_src[cb + j + (int)(e & 255u) + 1] = (int)(e >> 8);
        }
    } else {                            // fallback (oversized bucket)
        for (int i = lo + t; i < hi; i += 256) {
            unsigned e = ebuf[i];
            int ln = (int)(e & 255u);
            int p = atomicAdd(&cur[ln], 1);
            csr_src[cb + p + ln + 1] = (int)(e >> 8);
        }
    }
}

// ------------- single-pass softmax aggregate (no max subtraction) -----------
// Logits e = leaky_relu(a_src+a_dst) are O(±10): exp() cannot overflow fp32.
// One wave per node; lane l: head l>>4, channels 4*(l&15)..+3.
// 4-edge unroll, independent accumulators (best measured config: R7, 65.3us).
__global__ __launch_bounds__(256) void aggregate_kernel(
    const ushort* __restrict__ hb, const float* __restrict__ a_src,
    const float* __restrict__ a_dst, const int* __restrict__ rowptr,
    const int* __restrict__ csr_src, const float* __restrict__ bias,
    float* __restrict__ out, int N)
{
    int node = (int)((blockIdx.x * (size_t)blockDim.x + threadIdx.x) >> 6);
    int l = threadIdx.x & 63;
    if (node >= N) return;
    int start = rowptr[node];
    int end = rowptr[node + 1];
    int hd = l >> 4;
    float adh = a_dst[(size_t)node * NHEAD + hd];

    float4 acc0 = make_float4(0.f, 0.f, 0.f, 0.f);
    float4 acc1 = make_float4(0.f, 0.f, 0.f, 0.f);
    float4 acc2 = make_float4(0.f, 0.f, 0.f, 0.f);
    float4 acc3 = make_float4(0.f, 0.f, 0.f, 0.f);
    float s0 = 0.f, s1 = 0.f, s2 = 0.f, s3 = 0.f;

    int k = start;
    for (; k + 4 <= end; k += 4) {
        int sj0 = csr_src[k];
        int sj1 = csr_src[k + 1];
        int sj2 = csr_src[k + 2];
        int sj3 = csr_src[k + 3];
        float a0 = a_src[(size_t)sj0 * NHEAD + hd];
        float a1 = a_src[(size_t)sj1 * NHEAD + hd];
        float a2 = a_src[(size_t)sj2 * NHEAD + hd];
        float a3 = a_src[(size_t)sj3 * NHEAD + hd];
        ushort4 h0 = *(const ushort4*)(hb + ((size_t)sj0 << 8) + 4 * l);
        ushort4 h1 = *(const ushort4*)(hb + ((size_t)sj1 << 8) + 4 * l);
        ushort4 h2 = *(const ushort4*)(hb + ((size_t)sj2 << 8) + 4 * l);
        ushort4 h3 = *(const ushort4*)(hb + ((size_t)sj3 << 8) + 4 * l);
        float e0 = a0 + adh; e0 = fmaxf(e0, NEG_SLOPE * e0); float w0 = __expf(e0);
        float e1 = a1 + adh; e1 = fmaxf(e1, NEG_SLOPE * e1); float w1 = __expf(e1);
        float e2 = a2 + adh; e2 = fmaxf(e2, NEG_SLOPE * e2); float w2 = __expf(e2);
        float e3 = a3 + adh; e3 = fmaxf(e3, NEG_SLOPE * e3); float w3 = __expf(e3);
        s0 += w0; s1 += w1; s2 += w2; s3 += w3;
        acc0.x += w0 * bf2f(h0.x); acc0.y += w0 * bf2f(h0.y);
        acc0.z += w0 * bf2f(h0.z); acc0.w += w0 * bf2f(h0.w);
        acc1.x += w1 * bf2f(h1.x); acc1.y += w1 * bf2f(h1.y);
        acc1.z += w1 * bf2f(h1.z); acc1.w += w1 * bf2f(h1.w);
        acc2.x += w2 * bf2f(h2.x); acc2.y += w2 * bf2f(h2.y);
        acc2.z += w2 * bf2f(h2.z); acc2.w += w2 * bf2f(h2.w);
        acc3.x += w3 * bf2f(h3.x); acc3.y += w3 * bf2f(h3.y);
        acc3.z += w3 * bf2f(h3.z); acc3.w += w3 * bf2f(h3.w);
    }
    for (; k < end; ++k) {                       // tail (<=3 edges)
        int sj0 = csr_src[k];
        float a0 = a_src[(size_t)sj0 * NHEAD + hd];
        ushort4 h0 = *(const ushort4*)(hb + ((size_t)sj0 << 8) + 4 * l);
        float e0 = a0 + adh; e0 = fmaxf(e0, NEG_SLOPE * e0);
        float w0 = __expf(e0);
        s0 += w0;
        acc0.x += w0 * bf2f(h0.x); acc0.y += w0 * bf2f(h0.y);
        acc0.z += w0 * bf2f(h0.z); acc0.w += w0 * bf2f(h0.w);
    }

    float inv = 1.0f / (s0 + s1 + s2 + s3);      // per-head softmax denominator
    float4 acc;
    acc.x = (acc0.x + acc1.x + acc2.x + acc3.x) * inv;
    acc.y = (acc0.y + acc1.y + acc2.y + acc3.y) * inv;
    acc.z = (acc0.z + acc1.z + acc2.z + acc3.z) * inv;
    acc.w = (acc0.w + acc1.w + acc2.w + acc3.w) * inv;

    // reduce over heads: lanes l, l^16, l^32, l^48 hold same channels
    #pragma unroll
    for (int off = 16; off < 64; off <<= 1) {
        acc.x += __shfl_xor(acc.x, off, 64);
        acc.y += __shfl_xor(acc.y, off, 64);
        acc.z += __shfl_xor(acc.z, off, 64);
        acc.w += __shfl_xor(acc.w, off, 64);
    }
    if (l < 16) {
        float4 b4 = *(const float4*)(bias + 4 * l);
        float4 o;
        o.x = acc.x * 0.25f + b4.x;
        o.y = acc.y * 0.25f + b4.y;
        o.z = acc.z * 0.25f + b4.z;
        o.w = acc.w * 0.25f + b4.w;
        o.x = (o.x > 0.f) ? o.x : (__expf(o.x) - 1.f);
        o.y = (o.y > 0.f) ? o.y : (__expf(o.y) - 1.f);
        o.z = (o.z > 0.f) ? o.z : (__expf(o.z) - 1.f);
        o.w = (o.w > 0.f) ? o.w : (__expf(o.w) - 1.f);
        *(float4*)(out + (size_t)node * CH + 4 * l) = o;
    }
}

extern "C" void kernel_launch(void* const* d_in, const int* in_sizes, int n_in,
                              void* d_out, int out_size, void* d_ws, size_t ws_size,
                              hipStream_t stream)
{
    const float* x         = (const float*)d_in[0];
    const int*   edge_idx  = (const int*)d_in[1];
    const float* W         = (const float*)d_in[2];
    const float* att_src   = (const float*)d_in[3];
    const float* att_dst   = (const float*)d_in[4];
    const float* bias      = (const float*)d_in[5];
    float* out = (float*)d_out;

    const int N = in_sizes[0] / IN_F;
    const int E = in_sizes[1] / 2;
    const int Etot = E + N;
    const int NB = (N + 255) >> 8;     // coarse buckets (assumes N <= 65536)
    const int* srcp = edge_idx;
    const int* dstp = edge_idx + E;

    char* ws = (char*)d_ws;
    size_t off = 0;
    ushort*  hb     = (ushort*)(ws + off);   off += align256((size_t)N * HC * sizeof(ushort));
    ushort*  Wt     = (ushort*)(ws + off);   off += align256((size_t)HC * IN_F * sizeof(ushort));
    float*   a_src  = (float*)(ws + off);    off += align256((size_t)N * NHEAD * sizeof(float));
    float*   a_dst  = (float*)(ws + off);    off += align256((size_t)N * NHEAD * sizeof(float));
    int*     ccnt   = (int*)(ws + off);      off += align256(256 * CPAD * sizeof(int));
    int*     cur0   = (int*)(ws + off);      off += align256(256 * CPAD * sizeof(int));
    unsigned* ebuf  = (unsigned*)(ws + off); off += align256((size_t)E * sizeof(unsigned));
    int*     rowptr = (int*)(ws + off);      off += align256(((size_t)N + 1) * sizeof(int));
    int*     csrs   = (int*)(ws + off);      off += align256((size_t)Etot * sizeof(int));
    (void)ws_size; (void)n_in; (void)out_size;

    const int NTB = (N + 63) / 64;     // gemm tiles
    const int PBC = 208;               // fused count blocks (x2 = 416 slices)
    const int epbc = (E + 2 * PBC - 1) / (2 * PBC);
    const int PBS = (E + SC_EPB - 1) / SC_EPB;   // scatter blocks

    prep_kernel<<<IN_F * HC / 256, 256, 0, stream>>>(W, Wt, ccnt, cur0, rowptr, N, Etot);
    dim3 gg(NTB + PBC, 2);
    gemm_mfma_kernel<<<gg, 256, 0, stream>>>(x, Wt, att_src, att_dst, hb,
                                             a_src, a_dst, dstp, ccnt,
                                             E, epbc, NTB, NB, N);
    bucket_scatter<<<PBS, 256, 0, stream>>>(srcp, dstp, ccnt, cur0, ebuf, E);
    csr_build<<<NB, 256, 0, stream>>>(ebuf, ccnt, rowptr, csrs, N);
    aggregate_kernel<<<((size_t)N * 64 + 255) / 256, 256, 0, stream>>>(
        hb, a_src, a_dst, rowptr, csrs, bias, out, N);
}